// Round 1
// baseline (237.804 us; speedup 1.0000x reference)
//
#include <hip/hip_runtime.h>
#include <hip/hip_bf16.h>

#define N_IMG 32
#define CIN   128
#define INH   64
#define INW   64
#define COUT  256
#define OH    62
#define OW    62

typedef short          bf16x8 __attribute__((ext_vector_type(8)));
typedef unsigned short u16x8  __attribute__((ext_vector_type(8)));
typedef float          f32x4  __attribute__((ext_vector_type(4)));

__device__ __forceinline__ unsigned short f2bf(float x) {
    unsigned int u = __float_as_uint(x);
    u += 0x7fffu + ((u >> 16) & 1u);   // RNE
    return (unsigned short)(u >> 16);
}

// WT layout: [khw(9)][cg(16)][co(256)][i(8)] bf16, ci = cg*8 + i.
// This is exactly the MFMA A-fragment order: lane(q, m=lane&15) for a
// K-chunk (cb) reads 16 contiguous bytes at element (khw*16 + cb*4 + q, co).
__global__ void wt_transform_kernel(const float* __restrict__ Wsrc,
                                    unsigned short* __restrict__ WT) {
    int idx = blockIdx.x * 256 + threadIdx.x;          // < 9*16*256*8 = 294912
    int i   = idx & 7;
    int co  = (idx >> 3) & 255;
    int cgk = idx >> 11;            // khw*16 + cg
    int cg  = cgk & 15;
    int khw = cgk >> 4;             // 0..8
    int kh  = khw / 3, kw = khw - 3 * kh;
    int ci  = cg * 8 + i;
    WT[idx] = f2bf(Wsrc[co * (CIN * 9) + ci * 9 + kh * 3 + kw]);
}

// One workgroup per (img, oh). 4 waves; wave w owns co in [64w, 64w+64).
// GEMM: D[m=co][n=ow] += sum_k W[co][k] * X[k][ow],  k = (ci,kh,kw).
// A-frag (weights) direct from global WT; B-frag (input) from LDS rows.
__global__ __launch_bounds__(256, 2)
void conv_mfma_kernel(const float* __restrict__ In,
                      const unsigned short* __restrict__ WT,
                      float* __restrict__ Out) {
    // Lin[iw][ci_local(32)] bf16, XOR-swizzled 16B chunks: chunk' = chunk ^ (iw&3).
    // Row stride 64 B (16 dwords); swizzle balances all 32 banks for b128 ops.
    __shared__ unsigned short Lin[66 * 32];

    const int oh   = blockIdx.x;
    const int img  = blockIdx.y;
    const int tid  = threadIdx.x;
    const int wave = tid >> 6;
    const int lane = tid & 63;
    const int q    = lane >> 4;     // quad 0..3
    const int ml   = lane & 15;
    const int co_base = wave * 64;

    f32x4 acc[4][4];
    const f32x4 zero = {0.f, 0.f, 0.f, 0.f};
#pragma unroll
    for (int a = 0; a < 4; ++a)
#pragma unroll
        for (int b = 0; b < 4; ++b) acc[a][b] = zero;

    // zero pad rows 64,65 (ow=62,63 are padding; reads at iw=64,65 must be 0)
    if (tid < 32) ((unsigned int*)&Lin[64 * 32])[tid] = 0u;

    const int s_iw = tid & 63;      // staging: this thread's iw
    const int s_cg = tid >> 6;      // staging: 8-ci group 0..3 within the 32-ci block
    const bf16x8* WTv = (const bf16x8*)WT;

    for (int kh = 0; kh < 3; ++kh) {
        const int ih = oh + kh;
        for (int cb = 0; cb < 4; ++cb) {        // ci block of 32
            // ---- stage input rows (global loads issued before the barrier) ----
            const float* p = In + (((img * CIN + cb * 32 + s_cg * 8) * INH + ih) * INW + s_iw);
            u16x8 v;
#pragma unroll
            for (int i = 0; i < 8; ++i) v[i] = f2bf(p[i * (INH * INW)]);
            __syncthreads();   // previous iteration's readers done
            *(u16x8*)&Lin[s_iw * 32 + ((s_cg ^ (s_iw & 3)) << 3)] = v;
            __syncthreads();   // staging visible

            // ---- compute: 3 kw taps reuse the staged rows ----
#pragma unroll
            for (int kw = 0; kw < 3; ++kw) {
                const int khw = kh * 3 + kw;
                bf16x8 wf[4], xf[4];
#pragma unroll
                for (int mi = 0; mi < 4; ++mi)
                    wf[mi] = WTv[(khw * 16 + cb * 4 + q) * 256 + co_base + mi * 16 + ml];
#pragma unroll
                for (int ni = 0; ni < 4; ++ni) {
                    const int row = ni * 16 + ml + kw;
                    xf[ni] = *(const bf16x8*)&Lin[row * 32 + ((q ^ (row & 3)) << 3)];
                }
#pragma unroll
                for (int mi = 0; mi < 4; ++mi)
#pragma unroll
                    for (int ni = 0; ni < 4; ++ni)
                        acc[mi][ni] = __builtin_amdgcn_mfma_f32_16x16x32_bf16(
                            wf[mi], xf[ni], acc[mi][ni], 0, 0, 0);
            }
        }
    }

    // ---- epilogue: D[m=co][n=ow]; row = q*4+r, col = ml (verified C/D layout) ----
#pragma unroll
    for (int mi = 0; mi < 4; ++mi) {
#pragma unroll
        for (int r = 0; r < 4; ++r) {
            const int co = co_base + mi * 16 + q * 4 + r;
            float* op = Out + ((img * COUT + co) * OH + oh) * OW;
#pragma unroll
            for (int ni = 0; ni < 4; ++ni) {
                const int ow = ni * 16 + ml;
                if (ow < OW) op[ow] = acc[mi][ni][r];
            }
        }
    }
}

// Safety net if the workspace is too small for the transposed weights.
__global__ void conv_naive_kernel(const float* __restrict__ In,
                                  const float* __restrict__ Wt,
                                  float* __restrict__ Out) {
    int idx = blockIdx.x * 256 + threadIdx.x;
    const int total = N_IMG * COUT * OH * OW;
    if (idx >= total) return;
    int ow = idx % OW; int t = idx / OW;
    int oh = t % OH;   t /= OH;
    int co = t % COUT; int img = t / COUT;
    float s = 0.f;
    for (int ci = 0; ci < CIN; ++ci)
#pragma unroll
        for (int kh = 0; kh < 3; ++kh)
#pragma unroll
            for (int kw = 0; kw < 3; ++kw)
                s += In[((img * CIN + ci) * INH + oh + kh) * INW + ow + kw] *
                     Wt[co * CIN * 9 + ci * 9 + kh * 3 + kw];
    Out[idx] = s;
}

extern "C" void kernel_launch(void* const* d_in, const int* in_sizes, int n_in,
                              void* d_out, int out_size, void* d_ws, size_t ws_size,
                              hipStream_t stream) {
    const float* In   = (const float*)d_in[0];
    const float* Wsrc = (const float*)d_in[1];
    float* Out        = (float*)d_out;

    const size_t WT_BYTES = (size_t)9 * 16 * 256 * 8 * sizeof(unsigned short); // 589824
    if (ws_size >= WT_BYTES) {
        unsigned short* WT = (unsigned short*)d_ws;
        wt_transform_kernel<<<dim3(294912 / 256), dim3(256), 0, stream>>>(Wsrc, WT);
        conv_mfma_kernel<<<dim3(OH, N_IMG), dim3(256), 0, stream>>>(In, WT, Out);
    } else {
        const int total = N_IMG * COUT * OH * OW;
        conv_naive_kernel<<<dim3((total + 255) / 256), dim3(256), 0, stream>>>(In, Wsrc, Out);
    }
}